// Round 5
// baseline (291.058 us; speedup 1.0000x reference)
//
#include <hip/hip_runtime.h>

// B=8192, L=512, P=64, S=32, O=200
// Outputs (flat): [min1, min2, sub_min1, sub_min2, out(8192x200)]
// Structure: prep (transpose protoT/subpT + norm partials + init) ->
// phase1 (x@protoT, lanes=samples, B via uniform s_loads) -> scan/sort ->
// phase3 (per-group-chunk x@subpT[g] + stats + uniform-W GEMV) -> final.

#define NL 512
#define NP 64
#define NS 32
#define NO 200
#define NB 8192
#define MAXCH 192

// ws float-offsets
#define WS_SUM     0
#define WS_COLMIN  1
#define WS_SUBMIN  65
#define WS_GRPSUM  2113
#define WS_COUNT   2177
#define WS_PPPART  2241    // [8][64]
#define WS_SP2PART 2753    // [64][4][32]
#define WS_C2G     10945   // int[192]
#define WS_CBASE   11137   // uint[192]
#define WS_CMCNT   11329   // uint[192]
#define WS_OFFS    11521   // uint[65]
#define WS_SS      11586   // float[8192]
#define WS_IDX     19778   // int[8192]
#define WS_ORDER   27970   // uint[8192]
#define WS_PROTOT  40960   // float[512*64]
#define WS_SUBPT   81920   // float[64*512*32]

__device__ __forceinline__ unsigned encf(float f) {
  unsigned u = __float_as_uint(f);
  return (u & 0x80000000u) ? ~u : (u | 0x80000000u);
}
__device__ __forceinline__ float decf(unsigned m) {
  return __uint_as_float((m & 0x80000000u) ? (m ^ 0x80000000u) : ~m);
}
__device__ __forceinline__ float wred(float v) {
#pragma unroll
  for (int m = 32; m >= 1; m >>= 1) v += __shfl_xor(v, m, 64);
  return v;
}

// grid 265: 0..255 subp transpose (g=bid>>2, kb=bid&3); 256..263 proto
// transpose (kb); 264 init atomics.
__global__ __launch_bounds__(256) void hier_prep(const float* __restrict__ proto,
                                                 const float* __restrict__ subp,
                                                 float* __restrict__ ws) {
  __shared__ float lbuf[64 * 65];  // ts uses 32x129 (4128), tp uses 64x65
  __shared__ float part[256];
  const int bid = blockIdx.x, tid = threadIdx.x;

  if (bid == 264) {
    unsigned* wsu = (unsigned*)ws;
    if (tid == 0) ws[WS_SUM] = 0.f;
    if (tid < 64) {
      wsu[WS_COLMIN + tid] = 0xFFFFFFFFu;
      ws[WS_GRPSUM + tid] = 0.f;
      wsu[WS_COUNT + tid] = 0u;
    }
    for (int u = tid; u < NP * NS; u += 256) wsu[WS_SUBMIN + u] = 0xFFFFFFFFu;
    return;
  }

  if (bid < 256) {  // subp[g][s][k0..k0+127] -> subpT[g][k][s], sp2 partials
    const int g = bid >> 2, kb = bid & 3, k0 = kb * 128;
    const int r = tid >> 3, q = tid & 7;  // r: s-row, q: 16-k chunk
    const float4* src =
        (const float4*)(subp + ((size_t)g * NS + r) * NL + k0 + q * 16);
    float sq = 0.f;
#pragma unroll
    for (int i = 0; i < 4; ++i) {
      float4 v = src[i];
      sq += v.x * v.x + v.y * v.y + v.z * v.z + v.w * v.w;
      const int kL = q * 16 + i * 4;
      lbuf[r * 129 + kL + 0] = v.x;
      lbuf[r * 129 + kL + 1] = v.y;
      lbuf[r * 129 + kL + 2] = v.z;
      lbuf[r * 129 + kL + 3] = v.w;
    }
    part[tid] = sq;
    __syncthreads();
    if (tid < 32) {
      float a = 0.f;
#pragma unroll
      for (int j = 0; j < 8; ++j) a += part[tid * 8 + j];
      ws[WS_SP2PART + g * 128 + kb * 32 + tid] = a;
    }
#pragma unroll
    for (int i = 0; i < 4; ++i) {
      int f = i * 256 + tid;
      int kL = f >> 3, s4 = f & 7;
      float4 o;
      o.x = lbuf[(s4 * 4 + 0) * 129 + kL];
      o.y = lbuf[(s4 * 4 + 1) * 129 + kL];
      o.z = lbuf[(s4 * 4 + 2) * 129 + kL];
      o.w = lbuf[(s4 * 4 + 3) * 129 + kL];
      ((float4*)(ws + WS_SUBPT + ((size_t)g * NL + k0 + kL) * NS))[s4] = o;
    }
    return;
  }

  // proto[p][k0..k0+63] -> protoT[k][p], pp partials
  const int kb = bid - 256, k0 = kb * 64;
  const int r = tid >> 2, q = tid & 3;
  const float4* src = (const float4*)(proto + (size_t)r * NL + k0 + q * 16);
  float sq = 0.f;
#pragma unroll
  for (int i = 0; i < 4; ++i) {
    float4 v = src[i];
    sq += v.x * v.x + v.y * v.y + v.z * v.z + v.w * v.w;
    const int kL = q * 16 + i * 4;
    lbuf[r * 65 + kL + 0] = v.x;
    lbuf[r * 65 + kL + 1] = v.y;
    lbuf[r * 65 + kL + 2] = v.z;
    lbuf[r * 65 + kL + 3] = v.w;
  }
  part[tid] = sq;
  __syncthreads();
  if (tid < 64) {
    ws[WS_PPPART + kb * 64 + tid] =
        part[tid * 4] + part[tid * 4 + 1] + part[tid * 4 + 2] + part[tid * 4 + 3];
  }
#pragma unroll
  for (int i = 0; i < 4; ++i) {
    int f = i * 256 + tid;
    int kL = f >> 4, p4 = f & 15;
    float4 o;
    o.x = lbuf[(p4 * 4 + 0) * 65 + kL];
    o.y = lbuf[(p4 * 4 + 1) * 65 + kL];
    o.z = lbuf[(p4 * 4 + 2) * 65 + kL];
    o.w = lbuf[(p4 * 4 + 3) * 65 + kL];
    ((float4*)(ws + WS_PROTOT + (size_t)(k0 + kL) * 64))[p4] = o;
  }
}

// grid 128 x 256 thr: block = 64 samples; wave w holds protos 16w..16w+15.
// Per k: 1 ds_read_b32 (lane=sample) + 16 fmac vs uniform scalar B + ss fma.
__global__ __launch_bounds__(256) void hier_phase1(const float* __restrict__ x,
                                                   float* __restrict__ ws) {
  __shared__ float tile[64 * 32];
  __shared__ float pp_l[64];
  __shared__ float wmin[4][64];
  __shared__ int warg[4][64];
  __shared__ unsigned hist_l[64];

  const int tid = threadIdx.x;
  const int lane = tid & 63;
  const int w = __builtin_amdgcn_readfirstlane(tid >> 6);
  const int b0 = blockIdx.x * 64;
  const float* protoT = ws + WS_PROTOT;

  if (tid < 64) {
    float a = 0.f;
#pragma unroll
    for (int kb = 0; kb < 8; ++kb) a += ws[WS_PPPART + kb * 64 + tid];
    pp_l[tid] = a;
    hist_l[tid] = 0u;
  }

  float acc[16];
#pragma unroll
  for (int j = 0; j < 16; ++j) acc[j] = 0.f;
  float ssv = 0.f;

  const int sr = tid >> 2, sq = tid & 3;  // staging: row, 8-k chunk
  for (int kt = 0; kt < 16; ++kt) {
    __syncthreads();
    {
      const float4* xv =
          (const float4*)(x + (size_t)(b0 + sr) * NL + kt * 32 + sq * 8);
      float4 A = xv[0], Bv = xv[1];
      const int c0 = sq * 8;
      tile[sr * 32 + ((c0 + 0) ^ (sr & 31))] = A.x;
      tile[sr * 32 + ((c0 + 1) ^ (sr & 31))] = A.y;
      tile[sr * 32 + ((c0 + 2) ^ (sr & 31))] = A.z;
      tile[sr * 32 + ((c0 + 3) ^ (sr & 31))] = A.w;
      tile[sr * 32 + ((c0 + 4) ^ (sr & 31))] = Bv.x;
      tile[sr * 32 + ((c0 + 5) ^ (sr & 31))] = Bv.y;
      tile[sr * 32 + ((c0 + 6) ^ (sr & 31))] = Bv.z;
      tile[sr * 32 + ((c0 + 7) ^ (sr & 31))] = Bv.w;
    }
    __syncthreads();
#pragma unroll 4
    for (int kk = 0; kk < 32; ++kk) {
      float v = tile[lane * 32 + (kk ^ (lane & 31))];
      const float4* b4 =
          (const float4*)(protoT + (size_t)(kt * 32 + kk) * 64 + 16 * w);
      float4 B0 = b4[0], B1 = b4[1], B2 = b4[2], B3 = b4[3];
      ssv = fmaf(v, v, ssv);
      acc[0] = fmaf(v, B0.x, acc[0]);   acc[1] = fmaf(v, B0.y, acc[1]);
      acc[2] = fmaf(v, B0.z, acc[2]);   acc[3] = fmaf(v, B0.w, acc[3]);
      acc[4] = fmaf(v, B1.x, acc[4]);   acc[5] = fmaf(v, B1.y, acc[5]);
      acc[6] = fmaf(v, B1.z, acc[6]);   acc[7] = fmaf(v, B1.w, acc[7]);
      acc[8] = fmaf(v, B2.x, acc[8]);   acc[9] = fmaf(v, B2.y, acc[9]);
      acc[10] = fmaf(v, B2.z, acc[10]); acc[11] = fmaf(v, B2.w, acc[11]);
      acc[12] = fmaf(v, B3.x, acc[12]); acc[13] = fmaf(v, B3.y, acc[13]);
      acc[14] = fmaf(v, B3.z, acc[14]); acc[15] = fmaf(v, B3.w, acc[15]);
    }
  }

  // stats
  float d[16], rmin = 1e30f;
  int rarg = 0;
#pragma unroll
  for (int j = 0; j < 16; ++j) {
    d[j] = ssv + pp_l[16 * w + j] - 2.f * acc[j];
    if (d[j] < rmin) { rmin = d[j]; rarg = 16 * w + j; }
  }
  wmin[w][lane] = rmin;
  warg[w][lane] = rarg;
#pragma unroll
  for (int j = 0; j < 16; ++j) {
    float m = d[j];
#pragma unroll
    for (int sh = 1; sh <= 32; sh <<= 1) m = fminf(m, __shfl_xor(m, sh, 64));
    if (lane == 0) atomicMin((unsigned*)ws + WS_COLMIN + 16 * w + j, encf(m));
  }
  if (w == 0) ws[WS_SS + b0 + lane] = ssv;
  __syncthreads();
  if (w == 0) {
    float bm = wmin[0][lane];
    int ba = warg[0][lane];
#pragma unroll
    for (int ww = 1; ww < 4; ++ww) {
      if (wmin[ww][lane] < bm) { bm = wmin[ww][lane]; ba = warg[ww][lane]; }
    }
    ((int*)ws)[WS_IDX + b0 + lane] = ba;
    atomicAdd(&hist_l[ba], 1u);
    float s = wred(bm);
    if (lane == 0) atomicAdd(&ws[WS_SUM], s);
  }
  __syncthreads();
  if (tid < 64 && hist_l[tid]) atomicAdd((unsigned*)ws + WS_COUNT + tid, hist_l[tid]);
}

// 1 block x 256: offsets, chunk records, scatter-sort by group.
__global__ __launch_bounds__(256) void hier_scan(float* __restrict__ ws) {
  __shared__ unsigned cnt_l[64];
  __shared__ unsigned cur[64];
  const int tid = threadIdx.x;
  unsigned* wsu = (unsigned*)ws;
  for (int i = tid; i < MAXCH; i += 256) ((int*)ws)[WS_C2G + i] = -1;
  if (tid < 64) cnt_l[tid] = wsu[WS_COUNT + tid];
  __syncthreads();
  if (tid == 0) {
    unsigned run = 0;
    int nc = 0;
    for (int g = 0; g < NP; ++g) {
      wsu[WS_OFFS + g] = run;
      unsigned c = cnt_l[g];
      for (unsigned j = 0; j * 64 < c; ++j) {
        ((int*)ws)[WS_C2G + nc] = g;
        wsu[WS_CBASE + nc] = run + j * 64;
        unsigned mc = c - j * 64;
        wsu[WS_CMCNT + nc] = mc < 64u ? mc : 64u;
        ++nc;
      }
      run += c;
    }
    wsu[WS_OFFS + 64] = run;
  }
  __syncthreads();
  if (tid < 64) cur[tid] = wsu[WS_OFFS + tid];
  __syncthreads();
  const int* idx = (const int*)ws + WS_IDX;
  for (int b = tid; b < NB; b += 256) {
    int g = idx[b];
    unsigned pos = atomicAdd(&cur[g], 1u);
    wsu[WS_ORDER + pos] = (unsigned)b;
  }
}

// grid 192 x 256 thr: one 64-sample single-group chunk per block.
// wave w: subs 8w..8w+7 (uniform s_loads); epilogue: stats + GEMV (uniform W).
__global__ __launch_bounds__(256) void hier_phase3(const float* __restrict__ x,
                                                   const float* __restrict__ Wm,
                                                   const float* __restrict__ bias,
                                                   float* __restrict__ out,
                                                   float* __restrict__ ws) {
  __shared__ float tile[64 * 32];
  __shared__ float dsel_l[64 * 33];
  __shared__ unsigned rows_l[64];
  __shared__ float sp2_l[32];

  const int tid = threadIdx.x;
  const int lane = tid & 63;
  const int w = __builtin_amdgcn_readfirstlane(tid >> 6);
  const int c = blockIdx.x;
  int graw = ((const int*)ws)[WS_C2G + c];
  if (graw < 0) return;
  const int g = __builtin_amdgcn_readfirstlane(graw);
  const unsigned base =
      __builtin_amdgcn_readfirstlane(((const unsigned*)ws)[WS_CBASE + c]);
  const int mc =
      __builtin_amdgcn_readfirstlane((int)((const unsigned*)ws)[WS_CMCNT + c]);

  if (tid < 64) {
    int m = tid < mc ? tid : mc - 1;
    rows_l[tid] = ((const unsigned*)ws)[WS_ORDER + base + m];
  }
  if (tid < 32) {
    float a = 0.f;
#pragma unroll
    for (int kb = 0; kb < 4; ++kb) a += ws[WS_SP2PART + g * 128 + kb * 32 + tid];
    sp2_l[tid] = a;
  }

  float acc[8];
#pragma unroll
  for (int j = 0; j < 8; ++j) acc[j] = 0.f;

  const float* subpT = ws + WS_SUBPT + (size_t)g * NL * NS;
  const int sr = tid >> 2, sq = tid & 3;
  __syncthreads();
  const unsigned myrow = rows_l[lane];

  for (int kt = 0; kt < 16; ++kt) {
    if (kt) __syncthreads();
    {
      const float4* xv =
          (const float4*)(x + (size_t)rows_l[sr] * NL + kt * 32 + sq * 8);
      float4 A = xv[0], Bv = xv[1];
      const int c0 = sq * 8;
      tile[sr * 32 + ((c0 + 0) ^ (sr & 31))] = A.x;
      tile[sr * 32 + ((c0 + 1) ^ (sr & 31))] = A.y;
      tile[sr * 32 + ((c0 + 2) ^ (sr & 31))] = A.z;
      tile[sr * 32 + ((c0 + 3) ^ (sr & 31))] = A.w;
      tile[sr * 32 + ((c0 + 4) ^ (sr & 31))] = Bv.x;
      tile[sr * 32 + ((c0 + 5) ^ (sr & 31))] = Bv.y;
      tile[sr * 32 + ((c0 + 6) ^ (sr & 31))] = Bv.z;
      tile[sr * 32 + ((c0 + 7) ^ (sr & 31))] = Bv.w;
    }
    __syncthreads();
#pragma unroll 4
    for (int kk = 0; kk < 32; ++kk) {
      float v = tile[lane * 32 + (kk ^ (lane & 31))];
      const float4* b4 =
          (const float4*)(subpT + (size_t)(kt * 32 + kk) * NS + 8 * w);
      float4 B0 = b4[0], B1 = b4[1];
      acc[0] = fmaf(v, B0.x, acc[0]); acc[1] = fmaf(v, B0.y, acc[1]);
      acc[2] = fmaf(v, B0.z, acc[2]); acc[3] = fmaf(v, B0.w, acc[3]);
      acc[4] = fmaf(v, B1.x, acc[4]); acc[5] = fmaf(v, B1.y, acc[5]);
      acc[6] = fmaf(v, B1.z, acc[6]); acc[7] = fmaf(v, B1.w, acc[7]);
    }
  }

  const float ssv = ws[WS_SS + myrow];
#pragma unroll
  for (int j = 0; j < 8; ++j) {
    float dv = ssv + sp2_l[8 * w + j] - 2.f * acc[j];
    dsel_l[lane * 33 + 8 * w + j] = dv;
    float m = (lane < mc) ? dv : 1e30f;
#pragma unroll
    for (int sh = 1; sh <= 32; sh <<= 1) m = fminf(m, __shfl_xor(m, sh, 64));
    if (lane == 0) atomicMin((unsigned*)ws + WS_SUBMIN + g * NS + 8 * w + j, encf(m));
  }
  __syncthreads();
  if (w == 0) {
    float rm = 1e30f;
#pragma unroll
    for (int cc = 0; cc < NS; ++cc) rm = fminf(rm, dsel_l[lane * 33 + cc]);
    float val = (lane < mc) ? rm : 0.f;
    float s = wred(val);
    if (lane == 0) atomicAdd(&ws[WS_GRPSUM + g], s);
  }

  // GEMV: lane = sample; per-wave o-range (52/52/52/44), 4-o float4 stores.
  float dsr[NS];
#pragma unroll
  for (int cc = 0; cc < NS; ++cc) dsr[cc] = dsel_l[lane * 33 + cc];
  const float* wbase = Wm + (size_t)g * NO * NS;
  const float* bbase = bias + (size_t)g * NO;
  const int o0 = w * 52;
  const int no4 = (w < 3) ? 13 : 11;
  float* orow = out + (size_t)myrow * NO;
  for (int j4 = 0; j4 < no4; ++j4) {
    float r[4];
#pragma unroll
    for (int e = 0; e < 4; ++e) {
      const int o = o0 + 4 * j4 + e;
      const float4* wv = (const float4*)(wbase + (size_t)o * NS);
      float a = bbase[o];
#pragma unroll
      for (int k = 0; k < 8; ++k) {
        float4 w4 = wv[k];
        a += dsr[4 * k + 0] * w4.x + dsr[4 * k + 1] * w4.y +
             dsr[4 * k + 2] * w4.z + dsr[4 * k + 3] * w4.w;
      }
      r[e] = a;
    }
    float4 st = {r[0], r[1], r[2], r[3]};
    *(float4*)(orow + o0 + 4 * j4) = st;
  }
}

__global__ void hier_final(const float* __restrict__ ws, float* __restrict__ out4) {
  const int lane = threadIdx.x;  // 64 threads
  const unsigned* colmin = (const unsigned*)ws + WS_COLMIN;
  const unsigned* submin = (const unsigned*)ws + WS_SUBMIN;
  const float* grp_sum = ws + WS_GRPSUM;
  const unsigned* counts = (const unsigned*)ws + WS_COUNT;

  float min2 = wred(decf(colmin[lane])) * (1.0f / NP);

  unsigned cnt = counts[lane];
  float s32 = 0.f;
#pragma unroll
  for (int s = 0; s < NS; s++) s32 += decf(submin[lane * NS + s]);
  float sub1 = wred((cnt > 0u) ? s32 * (1.0f / NS) : 0.f) * (1.0f / NP);
  float sub2 = wred((cnt > 0u) ? grp_sum[lane] / (float)cnt : 0.f) * (1.0f / NP);

  if (lane == 0) {
    out4[0] = ws[WS_SUM] * (1.0f / NB);
    out4[1] = min2;
    out4[2] = sub1;
    out4[3] = sub2;
  }
}

extern "C" void kernel_launch(void* const* d_in, const int* in_sizes, int n_in,
                              void* d_out, int out_size, void* d_ws, size_t ws_size,
                              hipStream_t stream) {
  const float* x = (const float*)d_in[0];
  const float* proto = (const float*)d_in[1];
  const float* subp = (const float*)d_in[2];
  const float* Wm = (const float*)d_in[3];
  const float* bias = (const float*)d_in[4];
  float* outf = (float*)d_out;
  float* ws = (float*)d_ws;

  hipLaunchKernelGGL(hier_prep, dim3(265), dim3(256), 0, stream, proto, subp, ws);
  hipLaunchKernelGGL(hier_phase1, dim3(128), dim3(256), 0, stream, x, ws);
  hipLaunchKernelGGL(hier_scan, dim3(1), dim3(256), 0, stream, ws);
  hipLaunchKernelGGL(hier_phase3, dim3(MAXCH), dim3(256), 0, stream,
                     x, Wm, bias, outf + 4, ws);
  hipLaunchKernelGGL(hier_final, dim3(1), dim3(64), 0, stream, ws, outf);
}

// Round 6
// 175.685 us; speedup vs baseline: 1.6567x; 1.6567x over previous
//
#include <hip/hip_runtime.h>

// B=8192, L=512, P=64, S=32, O=200
// Outputs (flat): [min1, min2, sub_min1, sub_min2, out(8192x200)]
// MFMA (bf16 split hi/lo, 3-product) for both GEMM phases; stats epilogues
// carried from the verified round-5 kernel.

#define NL 512
#define NP 64
#define NS 32
#define NO 200
#define NB 8192
#define MAXCH 192

// float-region offsets (in floats)
#define WS_SUM     0
#define WS_COLMIN  1      // uint[64]
#define WS_SUBMIN  65     // uint[2048]
#define WS_GRPSUM  2113   // float[64]
#define WS_COUNT   2177   // uint[64]
#define WS_PP      2241   // float[64]
#define WS_SP2     2305   // float[2048]
#define WS_C2G     4353   // int[192]
#define WS_CBASE   4545   // uint[192]
#define WS_CMCNT   4737   // uint[192]
#define WS_OFFS    4929   // uint[65]
#define WS_SS      4994   // float[8192]
#define WS_IDX     13186  // int[8192]
#define WS_ORDER   21378  // uint[8192]  (ends 29570 floats = 118280 B)
// byte offsets for bf16 fragment arrays
#define WB_PB_HI   131072   // ushort[4096*8]  (proto frags)
#define WB_PB_LO   196608
#define WB_SPB_HI  262144   // ushort[131072*8] (subp frags, 2 MB)
#define WB_SPB_LO  2359296  // end 4456448 B

typedef __attribute__((ext_vector_type(8))) short short8v;
typedef __attribute__((ext_vector_type(4))) float f32x4;

__device__ __forceinline__ unsigned encf(float f) {
  unsigned u = __float_as_uint(f);
  return (u & 0x80000000u) ? ~u : (u | 0x80000000u);
}
__device__ __forceinline__ float decf(unsigned m) {
  return __uint_as_float((m & 0x80000000u) ? (m ^ 0x80000000u) : ~m);
}
__device__ __forceinline__ float wred(float v) {
#pragma unroll
  for (int m = 32; m >= 1; m >>= 1) v += __shfl_xor(v, m, 64);
  return v;
}
__device__ __forceinline__ float dot4(const float4& a, const float4& b) {
  return a.x * b.x + a.y * b.y + a.z * b.z + a.w * b.w;
}
__device__ __forceinline__ unsigned short f2bf(float f) {
  unsigned u = __float_as_uint(f);
  u += 0x7FFFu + ((u >> 16) & 1u);
  return (unsigned short)(u >> 16);
}
__device__ __forceinline__ float bf2f(unsigned short h) {
  return __uint_as_float(((unsigned)h) << 16);
}
// convert 8 fp32 -> hi/lo bf16 frags, accumulate sum of squares (fp32-exact)
__device__ __forceinline__ void cvt8(const float4& v0, const float4& v1,
                                     short8v& hi, short8v& lo, float& ss) {
  float vs[8] = {v0.x, v0.y, v0.z, v0.w, v1.x, v1.y, v1.z, v1.w};
#pragma unroll
  for (int i = 0; i < 8; ++i) {
    ss = fmaf(vs[i], vs[i], ss);
    unsigned short h = f2bf(vs[i]);
    hi[i] = (short)h;
    lo[i] = (short)f2bf(vs[i] - bf2f(h));
  }
}

// grid 562:
//  0..511  : subp B-fragments (hi/lo)
//  512..527: proto B-fragments
//  528..559: sp2 norms (64 rows each)
//  560     : pp norms
//  561     : init stats
__global__ __launch_bounds__(256) void hier_prep(const float* __restrict__ proto,
                                                 const float* __restrict__ subp,
                                                 float* __restrict__ ws) {
  __shared__ float part[256];
  const int bid = blockIdx.x, tid = threadIdx.x;
  unsigned short* sph = (unsigned short*)((char*)ws + WB_SPB_HI);
  unsigned short* spl = (unsigned short*)((char*)ws + WB_SPB_LO);
  unsigned short* pbh = (unsigned short*)((char*)ws + WB_PB_HI);
  unsigned short* pbl = (unsigned short*)((char*)ws + WB_PB_LO);

  if (bid < 512) {
    const int fi = bid * 256 + tid;           // 0..131071
    const int l = fi & 63, nt = (fi >> 6) & 1, kt = (fi >> 7) & 15, g = fi >> 11;
    const int s = nt * 16 + (l & 15), k0 = kt * 32 + (l >> 4) * 8;
    const float* src = subp + ((size_t)(g * NS + s)) * NL + k0;
    float4 a = *(const float4*)src, b = *(const float4*)(src + 4);
    float vs[8] = {a.x, a.y, a.z, a.w, b.x, b.y, b.z, b.w};
#pragma unroll
    for (int i = 0; i < 8; ++i) {
      unsigned short h = f2bf(vs[i]);
      sph[(size_t)fi * 8 + i] = h;
      spl[(size_t)fi * 8 + i] = f2bf(vs[i] - bf2f(h));
    }
    return;
  }
  if (bid < 528) {
    const int pi = (bid - 512) * 256 + tid;   // 0..4095
    const int l = pi & 63, nt = (pi >> 6) & 3, kt = pi >> 8;
    const int p = nt * 16 + (l & 15), k0 = kt * 32 + (l >> 4) * 8;
    const float* src = proto + (size_t)p * NL + k0;
    float4 a = *(const float4*)src, b = *(const float4*)(src + 4);
    float vs[8] = {a.x, a.y, a.z, a.w, b.x, b.y, b.z, b.w};
#pragma unroll
    for (int i = 0; i < 8; ++i) {
      unsigned short h = f2bf(vs[i]);
      pbh[(size_t)pi * 8 + i] = h;
      pbl[(size_t)pi * 8 + i] = f2bf(vs[i] - bf2f(h));
    }
    return;
  }
  if (bid < 560) {  // sp2: rows (g*32+s) in [ (bid-528)*64, +64 )
    const int r = (bid - 528) * 64 + (tid >> 2), q = tid & 3;
    const float4* src = (const float4*)(subp + (size_t)r * NL) + q * 32;
    float a = 0.f;
#pragma unroll
    for (int j = 0; j < 32; ++j) a += dot4(src[j], src[j]);
    part[tid] = a;
    __syncthreads();
    if (tid < 64)
      ws[WS_SP2 + (bid - 528) * 64 + tid] =
          part[4 * tid] + part[4 * tid + 1] + part[4 * tid + 2] + part[4 * tid + 3];
    return;
  }
  if (bid == 560) {
    const int r = tid >> 2, q = tid & 3;
    const float4* src = (const float4*)(proto + (size_t)r * NL) + q * 32;
    float a = 0.f;
#pragma unroll
    for (int j = 0; j < 32; ++j) a += dot4(src[j], src[j]);
    part[tid] = a;
    __syncthreads();
    if (tid < 64)
      ws[WS_PP + tid] =
          part[4 * tid] + part[4 * tid + 1] + part[4 * tid + 2] + part[4 * tid + 3];
    return;
  }
  // init
  unsigned* wsu = (unsigned*)ws;
  if (tid == 0) ws[WS_SUM] = 0.f;
  if (tid < 64) {
    wsu[WS_COLMIN + tid] = 0xFFFFFFFFu;
    ws[WS_GRPSUM + tid] = 0.f;
    wsu[WS_COUNT + tid] = 0u;
  }
  for (int u = tid; u < NP * NS; u += 256) wsu[WS_SUBMIN + u] = 0xFFFFFFFFu;
}

// grid 128 x 256: block = 64 samples; wave = 16 samples x all 64 protos.
// Per k-step: 2 A-loads + cvt, 8 coalesced B-frag loads, 12 MFMA.
__global__ __launch_bounds__(256) void hier_phase1(const float* __restrict__ x,
                                                   float* __restrict__ ws) {
  __shared__ unsigned hist_l[64];
  const int tid = threadIdx.x, lane = tid & 63, w = tid >> 6;
  const int c = lane & 15, g4 = lane >> 4;
  const int b0 = blockIdx.x * 64;
  const short8v* PBH = (const short8v*)((const char*)ws + WB_PB_HI);
  const short8v* PBL = (const short8v*)((const char*)ws + WB_PB_LO);
  if (tid < 64) hist_l[tid] = 0u;
  __syncthreads();

  const int row = b0 + w * 16 + c;
  const float* xrow = x + (size_t)row * NL + g4 * 8;
  f32x4 acc[4];
#pragma unroll
  for (int nt = 0; nt < 4; ++nt) acc[nt] = (f32x4){0.f, 0.f, 0.f, 0.f};
  float ssv = 0.f;

#pragma unroll 2
  for (int kt = 0; kt < 16; ++kt) {
    float4 v0 = *(const float4*)(xrow + kt * 32);
    float4 v1 = *(const float4*)(xrow + kt * 32 + 4);
    short8v ah, al;
    cvt8(v0, v1, ah, al, ssv);
    const short8v* BH = PBH + (size_t)(kt * 4) * 64 + lane;
    const short8v* BL = PBL + (size_t)(kt * 4) * 64 + lane;
#pragma unroll
    for (int nt = 0; nt < 4; ++nt) {
      short8v bh = BH[nt * 64];
      short8v bl = BL[nt * 64];
      acc[nt] = __builtin_amdgcn_mfma_f32_16x16x32_bf16(ah, bh, acc[nt], 0, 0, 0);
      acc[nt] = __builtin_amdgcn_mfma_f32_16x16x32_bf16(ah, bl, acc[nt], 0, 0, 0);
      acc[nt] = __builtin_amdgcn_mfma_f32_16x16x32_bf16(al, bh, acc[nt], 0, 0, 0);
    }
  }

  // ss: lane holds partial over k-slice of row (b0+w*16+c); combine k-groups
  ssv += __shfl_xor(ssv, 16, 64);
  ssv += __shfl_xor(ssv, 32, 64);
  if (lane < 16) ws[WS_SS + b0 + w * 16 + lane] = ssv;
  float ssm[4];
#pragma unroll
  for (int r = 0; r < 4; ++r) ssm[r] = __shfl(ssv, g4 * 4 + r, 64);

  // D layout: lane holds (m = g4*4+r, n = nt*16+c)
  float dv[4][4];
#pragma unroll
  for (int nt = 0; nt < 4; ++nt) {
    float ppv = ws[WS_PP + nt * 16 + c];
#pragma unroll
    for (int r = 0; r < 4; ++r) dv[nt][r] = ssm[r] + ppv - 2.f * acc[nt][r];
  }
  // per-sample (row) min+arg over 64 protos
  float rmin[4];
  int rarg[4];
#pragma unroll
  for (int r = 0; r < 4; ++r) {
    rmin[r] = 1e30f; rarg[r] = 0;
#pragma unroll
    for (int nt = 0; nt < 4; ++nt)
      if (dv[nt][r] < rmin[r]) { rmin[r] = dv[nt][r]; rarg[r] = nt * 16 + c; }
  }
#pragma unroll
  for (int m = 1; m <= 8; m <<= 1) {
#pragma unroll
    for (int r = 0; r < 4; ++r) {
      float om = __shfl_xor(rmin[r], m, 64);
      int oa = __shfl_xor(rarg[r], m, 64);
      if (om < rmin[r] || (om == rmin[r] && oa < rarg[r])) { rmin[r] = om; rarg[r] = oa; }
    }
  }
  // per-proto column min over the wave's 16 samples
#pragma unroll
  for (int nt = 0; nt < 4; ++nt) {
    float cm = fminf(fminf(dv[nt][0], dv[nt][1]), fminf(dv[nt][2], dv[nt][3]));
    cm = fminf(cm, __shfl_xor(cm, 16, 64));
    cm = fminf(cm, __shfl_xor(cm, 32, 64));
    if (lane < 16) atomicMin((unsigned*)ws + WS_COLMIN + nt * 16 + lane, encf(cm));
  }
  // idx, counts, min1-sum
  float rsum = 0.f;
  if (c == 0) {
#pragma unroll
    for (int r = 0; r < 4; ++r) {
      ((int*)ws)[WS_IDX + b0 + w * 16 + g4 * 4 + r] = rarg[r];
      atomicAdd(&hist_l[rarg[r]], 1u);
      rsum += rmin[r];
    }
  }
  rsum = wred(rsum);
  if (lane == 0) atomicAdd(&ws[WS_SUM], rsum);
  __syncthreads();
  if (tid < 64 && hist_l[tid]) atomicAdd((unsigned*)ws + WS_COUNT + tid, hist_l[tid]);
}

// 1 block x 256: offsets, chunk records, scatter-sort by group.
__global__ __launch_bounds__(256) void hier_scan(float* __restrict__ ws) {
  __shared__ unsigned cnt_l[64];
  __shared__ unsigned cur[64];
  const int tid = threadIdx.x;
  unsigned* wsu = (unsigned*)ws;
  for (int i = tid; i < MAXCH; i += 256) ((int*)ws)[WS_C2G + i] = -1;
  if (tid < 64) cnt_l[tid] = wsu[WS_COUNT + tid];
  __syncthreads();
  if (tid == 0) {
    unsigned run = 0;
    int nc = 0;
    for (int g = 0; g < NP; ++g) {
      wsu[WS_OFFS + g] = run;
      unsigned cc = cnt_l[g];
      for (unsigned j = 0; j * 64 < cc; ++j) {
        ((int*)ws)[WS_C2G + nc] = g;
        wsu[WS_CBASE + nc] = run + j * 64;
        unsigned mc = cc - j * 64;
        wsu[WS_CMCNT + nc] = mc < 64u ? mc : 64u;
        ++nc;
      }
      run += cc;
    }
    wsu[WS_OFFS + 64] = run;
  }
  __syncthreads();
  if (tid < 64) cur[tid] = wsu[WS_OFFS + tid];
  __syncthreads();
  const int* idx = (const int*)ws + WS_IDX;
  for (int b = tid; b < NB; b += 256) {
    int g = idx[b];
    unsigned pos = atomicAdd(&cur[g], 1u);
    wsu[WS_ORDER + pos] = (unsigned)b;
  }
}

// grid 192 x 256: one 64-sample single-group chunk; wave = 16 samples x 32 subs.
__global__ __launch_bounds__(256) void hier_phase3(const float* __restrict__ x,
                                                   const float* __restrict__ Wm,
                                                   const float* __restrict__ bias,
                                                   float* __restrict__ out,
                                                   float* __restrict__ ws) {
  __shared__ unsigned rows_l[64];
  __shared__ float ss_l[64];
  __shared__ float sp2_l[32];
  __shared__ float dsel_l[64 * 33];
  const int tid = threadIdx.x, lane = tid & 63, w = tid >> 6;
  const int c = lane & 15, g4 = lane >> 4;
  const int ch = blockIdx.x;
  const int graw = ((const int*)ws)[WS_C2G + ch];
  if (graw < 0) return;
  const int g = graw;
  const unsigned base = ((const unsigned*)ws)[WS_CBASE + ch];
  const int mc = (int)((const unsigned*)ws)[WS_CMCNT + ch];

  if (tid < 64) {
    int m = tid < mc ? tid : mc - 1;
    rows_l[tid] = ((const unsigned*)ws)[WS_ORDER + base + m];
  }
  __syncthreads();
  if (tid < 64) ss_l[tid] = ws[WS_SS + rows_l[tid]];
  if (tid < 32) sp2_l[tid] = ws[WS_SP2 + g * NS + tid];
  __syncthreads();

  const short8v* SPH = (const short8v*)((const char*)ws + WB_SPB_HI);
  const short8v* SPL = (const short8v*)((const char*)ws + WB_SPB_LO);
  const float* xrow = x + (size_t)rows_l[w * 16 + c] * NL + g4 * 8;

  f32x4 acc[2];
  acc[0] = (f32x4){0.f, 0.f, 0.f, 0.f};
  acc[1] = (f32x4){0.f, 0.f, 0.f, 0.f};
  float ssv = 0.f;  // unused result, cvt8 needs it

#pragma unroll 2
  for (int kt = 0; kt < 16; ++kt) {
    float4 v0 = *(const float4*)(xrow + kt * 32);
    float4 v1 = *(const float4*)(xrow + kt * 32 + 4);
    short8v ah, al;
    cvt8(v0, v1, ah, al, ssv);
    const short8v* BH = SPH + ((size_t)(g * 16 + kt) * 2) * 64 + lane;
    const short8v* BL = SPL + ((size_t)(g * 16 + kt) * 2) * 64 + lane;
#pragma unroll
    for (int nt = 0; nt < 2; ++nt) {
      short8v bh = BH[nt * 64];
      short8v bl = BL[nt * 64];
      acc[nt] = __builtin_amdgcn_mfma_f32_16x16x32_bf16(ah, bh, acc[nt], 0, 0, 0);
      acc[nt] = __builtin_amdgcn_mfma_f32_16x16x32_bf16(ah, bl, acc[nt], 0, 0, 0);
      acc[nt] = __builtin_amdgcn_mfma_f32_16x16x32_bf16(al, bh, acc[nt], 0, 0, 0);
    }
  }

  float dv[2][4];
#pragma unroll
  for (int nt = 0; nt < 2; ++nt) {
    float s2 = sp2_l[nt * 16 + c];
#pragma unroll
    for (int r = 0; r < 4; ++r) {
      dv[nt][r] = ss_l[w * 16 + g4 * 4 + r] + s2 - 2.f * acc[nt][r];
      dsel_l[(w * 16 + g4 * 4 + r) * 33 + nt * 16 + c] = dv[nt][r];
    }
  }
  // per-sub column min (dups in padded rows are idempotent for min)
#pragma unroll
  for (int nt = 0; nt < 2; ++nt) {
    float cm = fminf(fminf(dv[nt][0], dv[nt][1]), fminf(dv[nt][2], dv[nt][3]));
    cm = fminf(cm, __shfl_xor(cm, 16, 64));
    cm = fminf(cm, __shfl_xor(cm, 32, 64));
    if (lane < 16) atomicMin((unsigned*)ws + WS_SUBMIN + g * NS + nt * 16 + lane, encf(cm));
  }
  // per-sample min over 32 subs -> grp_sum (mask padded)
  float rmin[4];
#pragma unroll
  for (int r = 0; r < 4; ++r) rmin[r] = fminf(dv[0][r], dv[1][r]);
#pragma unroll
  for (int m = 1; m <= 8; m <<= 1) {
#pragma unroll
    for (int r = 0; r < 4; ++r) rmin[r] = fminf(rmin[r], __shfl_xor(rmin[r], m, 64));
  }
  float rsum = 0.f;
  if (c == 0) {
#pragma unroll
    for (int r = 0; r < 4; ++r) {
      int sm = w * 16 + g4 * 4 + r;
      if (sm < mc) rsum += rmin[r];
    }
  }
  rsum = wred(rsum);
  if (lane == 0) atomicAdd(&ws[WS_GRPSUM + g], rsum);
  __syncthreads();

  // GEMV: lane = chunk sample; wave w covers o-range (52/52/52/44)
  const unsigned myrow = rows_l[lane];
  float dsr[NS];
#pragma unroll
  for (int cc = 0; cc < NS; ++cc) dsr[cc] = dsel_l[lane * 33 + cc];
  const float* wbase = Wm + (size_t)g * NO * NS;
  const float* bbase = bias + (size_t)g * NO;
  const int o0 = w * 52;
  const int no4 = (w < 3) ? 13 : 11;
  float* orow = out + (size_t)myrow * NO;
  for (int j4 = 0; j4 < no4; ++j4) {
    float rr[4];
#pragma unroll
    for (int e = 0; e < 4; ++e) {
      const int o = o0 + 4 * j4 + e;
      const float4* wv = (const float4*)(wbase + (size_t)o * NS);
      float a = bbase[o];
#pragma unroll
      for (int k = 0; k < 8; ++k) {
        float4 w4 = wv[k];
        a += dsr[4 * k + 0] * w4.x + dsr[4 * k + 1] * w4.y +
             dsr[4 * k + 2] * w4.z + dsr[4 * k + 3] * w4.w;
      }
      rr[e] = a;
    }
    float4 st = {rr[0], rr[1], rr[2], rr[3]};
    *(float4*)(orow + o0 + 4 * j4) = st;
  }
}

__global__ void hier_final(const float* __restrict__ ws, float* __restrict__ out4) {
  const int lane = threadIdx.x;  // 64 threads
  const unsigned* colmin = (const unsigned*)ws + WS_COLMIN;
  const unsigned* submin = (const unsigned*)ws + WS_SUBMIN;
  const float* grp_sum = ws + WS_GRPSUM;
  const unsigned* counts = (const unsigned*)ws + WS_COUNT;

  float min2 = wred(decf(colmin[lane])) * (1.0f / NP);

  unsigned cnt = counts[lane];
  float s32 = 0.f;
#pragma unroll
  for (int s = 0; s < NS; s++) s32 += decf(submin[lane * NS + s]);
  float sub1 = wred((cnt > 0u) ? s32 * (1.0f / NS) : 0.f) * (1.0f / NP);
  float sub2 = wred((cnt > 0u) ? grp_sum[lane] / (float)cnt : 0.f) * (1.0f / NP);

  if (lane == 0) {
    out4[0] = ws[WS_SUM] * (1.0f / NB);
    out4[1] = min2;
    out4[2] = sub1;
    out4[3] = sub2;
  }
}

extern "C" void kernel_launch(void* const* d_in, const int* in_sizes, int n_in,
                              void* d_out, int out_size, void* d_ws, size_t ws_size,
                              hipStream_t stream) {
  const float* x = (const float*)d_in[0];
  const float* proto = (const float*)d_in[1];
  const float* subp = (const float*)d_in[2];
  const float* Wm = (const float*)d_in[3];
  const float* bias = (const float*)d_in[4];
  float* outf = (float*)d_out;
  float* ws = (float*)d_ws;

  hipLaunchKernelGGL(hier_prep, dim3(562), dim3(256), 0, stream, proto, subp, ws);
  hipLaunchKernelGGL(hier_phase1, dim3(128), dim3(256), 0, stream, x, ws);
  hipLaunchKernelGGL(hier_scan, dim3(1), dim3(256), 0, stream, ws);
  hipLaunchKernelGGL(hier_phase3, dim3(MAXCH), dim3(256), 0, stream,
                     x, Wm, bias, outf + 4, ws);
  hipLaunchKernelGGL(hier_final, dim3(1), dim3(64), 0, stream, ws, outf);
}